// Round 4
// baseline (1563.162 us; speedup 1.0000x reference)
//
#include <hip/hip_runtime.h>

// PVDST semseg, MI355X/gfx950. I/O dtype is FP32 (reference is jnp.float32;
// the harness's "bf16" label string is hard-coded). Round-3 root-cause fix:
// rounds 0-2 read fp32 buffers as bf16 -> NaN KNN distances -> insert16 never
// fired -> sentinel 0x7fffffff leaked into idx -> attn gather OOB -> abort.
// Design:
//   - token-major (T=B*N, C) bf16 activations -> LDS-free MFMA GEMMs with
//     contiguous 16B/lane fragment loads straight from global (L2-served).
//   - weights converted fp32->bf16 once per call into scratch (prepass).
//   - KNN in exact fp32 (matches np rounding), stable strict-< top-16.
//   - cls1's broadcast-g half folded into per-(b,o) fp32 term (gterm).
//   - scratch = 112 MB device .bss global, offsets only, no aliasing.

#define NB 4
#define NP 4096
#define NT 16384   // NB*NP tokens

#define SCRATCH_BYTES (112u*1024u*1024u)
__device__ __align__(256) unsigned char g_scratch[SCRATCH_BYTES];

typedef __attribute__((ext_vector_type(8))) short short8;   // 8 x bf16 MFMA frag
typedef __attribute__((ext_vector_type(4))) float f32x4;    // MFMA acc
typedef __attribute__((ext_vector_type(4))) unsigned short ushort4v;

__device__ __forceinline__ float bf2f(unsigned short u){
  unsigned int v = ((unsigned int)u) << 16;
  return __builtin_bit_cast(float, v);
}
__device__ __forceinline__ unsigned short f2bf(float f){
  unsigned int x = __builtin_bit_cast(unsigned int, f);
  x += 0x7fffu + ((x >> 16) & 1u);     // RNE
  return (unsigned short)(x >> 16);
}
// numpy-matched: ((x*x)+(y*y))+(z*z), each op rounded (no fma contraction)
__device__ __forceinline__ float sq3(float x, float y, float z){
  return __fadd_rn(__fadd_rn(__fmul_rn(x,x), __fmul_rn(y,y)), __fmul_rn(z,z));
}

// sorted ascending top-16 insertion; strict < => earlier index wins ties.
// Sentinel index 0 (in-range) -- defense vs degenerate/NaN distances.
__device__ __forceinline__ void insert16(float (&dist)[16], int (&ind)[16], float d, int m){
  if (d < dist[15]) {
    if (d < dist[7]) {
      #pragma unroll
      for (int j=15;j>8;--j){ dist[j]=dist[j-1]; ind[j]=ind[j-1]; }
      dist[8]=dist[7]; ind[8]=ind[7];
      float dc=d; int ic=m;
      #pragma unroll
      for (int j=0;j<8;++j){
        if (dc<dist[j]){ float td=dist[j]; dist[j]=dc; dc=td; int ti=ind[j]; ind[j]=ic; ic=ti; }
      }
    } else {
      float dc=d; int ic=m;
      #pragma unroll
      for (int j=8;j<16;++j){
        if (dc<dist[j]){ float td=dist[j]; dist[j]=dc; dc=td; int ti=ind[j]; ind[j]=ic; ic=ti; }
      }
    }
  }
}

// ---------------- weight fp32 -> bf16 conversion prepass ----------------
__global__ __launch_bounds__(256) void cvt_flat(const float* __restrict__ src,
                                                unsigned dstOff, int n)
{
  unsigned short* dst = (unsigned short*)(g_scratch + dstOff);
  for (int i = blockIdx.x*256 + threadIdx.x; i < n; i += gridDim.x*256)
    dst[i] = f2bf(src[i]);
}
// cls_w1 x-half: rows x 1024 cols out of pitch-3072 rows
__global__ __launch_bounds__(256) void cvt_pitch1024(const float* __restrict__ src,
                                                     unsigned dstOff, int n /*rows<<10*/)
{
  unsigned short* dst = (unsigned short*)(g_scratch + dstOff);
  for (int i = blockIdx.x*256 + threadIdx.x; i < n; i += gridDim.x*256){
    int r = i >> 10, c = i & 1023;
    dst[i] = f2bf(src[(size_t)r*3072 + c]);
  }
}

// ---------------- KNN (exact fp32) ----------------
// grid (16 qchunks, 4 cchunks, B), block 256. One thread = one query vs 1024
// candidates staged in LDS as float4(x,y,z,sq).
__global__ __launch_bounds__(256) void knn_scan(const float* __restrict__ in,
                                                unsigned pdOff, unsigned piOff)
{
  float* pdist = (float*)(g_scratch + pdOff);
  int*   pidx  = (int*)  (g_scratch + piOff);
  __shared__ float4 sp[1024];
  int b = blockIdx.z, qc = blockIdx.x, cc = blockIdx.y;
  const float* xb = in + (size_t)b*9*NP;
  int base = cc*1024;
  for (int i = threadIdx.x; i < 1024; i += 256) {
    float x = xb[base+i], y = xb[NP+base+i], z = xb[2*NP+base+i];
    sp[i] = make_float4(x,y,z,sq3(x,y,z));
  }
  __syncthreads();
  int n = qc*256 + threadIdx.x;
  float xn=xb[n], yn=xb[NP+n], zn=xb[2*NP+n];
  float sqn = sq3(xn,yn,zn);
  float dist[16]; int ind[16];
  #pragma unroll
  for (int j=0;j<16;j++){ dist[j]=3.0e38f; ind[j]=0; }
  for (int mm=0; mm<1024; ++mm){
    float4 p = sp[mm];
    float dot = __fadd_rn(__fadd_rn(__fmul_rn(xn,p.x), __fmul_rn(yn,p.y)), __fmul_rn(zn,p.z));
    float d = __fsub_rn(__fadd_rn(sqn, p.w), __fmul_rn(2.0f, dot));
    insert16(dist, ind, d, base+mm);
  }
  size_t o = ((size_t)((b*4 + cc)*NP + n))*16;
  #pragma unroll
  for (int j=0;j<16;j++){ pdist[o+j]=dist[j]; pidx[o+j]=ind[j]; }
}

// grid 64, block 256: merge 4 chunk lists (chunk order = ascending index =>
// strict < keeps stable tie-breaking).
__global__ __launch_bounds__(256) void knn_merge(unsigned pdOff, unsigned piOff, unsigned idxOff)
{
  const float* pdist = (const float*)(g_scratch + pdOff);
  const int*   pidx  = (const int*)  (g_scratch + piOff);
  int*         idxOut= (int*)        (g_scratch + idxOff);
  int t = blockIdx.x*256 + threadIdx.x;
  int b = t >> 12, n = t & 4095;
  float dist[16]; int ind[16];
  #pragma unroll
  for (int j=0;j<16;j++){ dist[j]=3.0e38f; ind[j]=0; }
  for (int cc=0; cc<4; ++cc){
    size_t o = ((size_t)((b*4 + cc)*NP + n))*16;
    for (int j=0;j<16;j++) insert16(dist, ind, pdist[o+j], pidx[o+j]);
  }
  #pragma unroll
  for (int j=0;j<16;j++) idxOut[t*16+j] = ind[j];
}

// ---------------- embedding conv1 (Cin=9), fp32 in -> bf16 out ----------------
__global__ __launch_bounds__(256) void emb1_kernel(const float* __restrict__ in,
                                                   const float* __restrict__ w1,
                                                   const float* __restrict__ s1,
                                                   const float* __restrict__ b1,
                                                   unsigned x1Off)
{
  unsigned short* x1 = (unsigned short*)(g_scratch + x1Off);
  __shared__ float wf[128*9], sf[128], bf_[128];
  for (int i=threadIdx.x;i<128*9;i+=256) wf[i]=w1[i];
  if (threadIdx.x < 128){ sf[threadIdx.x]=s1[threadIdx.x]; bf_[threadIdx.x]=b1[threadIdx.x]; }
  __syncthreads();
  int t = blockIdx.x*256 + threadIdx.x;
  int b = t >> 12, n = t & 4095;
  float v[9];
  #pragma unroll
  for (int c=0;c<9;c++) v[c] = in[((size_t)b*9 + c)*NP + n];
  for (int o=0;o<128;o+=2){
    float a0=0.f, a1=0.f;
    #pragma unroll
    for (int c=0;c<9;c++){ a0 += wf[o*9+c]*v[c]; a1 += wf[(o+1)*9+c]*v[c]; }
    a0 = fmaxf(sf[o]*a0 + bf_[o], 0.f);
    a1 = fmaxf(sf[o+1]*a1 + bf_[o+1], 0.f);
    unsigned pk = (unsigned)f2bf(a0) | ((unsigned)f2bf(a1) << 16);
    *(unsigned*)(x1 + (size_t)t*128 + o) = pk;
  }
}

// ---------------- generic token-major MFMA GEMM (bf16 in/out) ----------------
// out[token][m] = epi( sum_k W[m][k] * X[token][k] ); W and X are bf16 in
// scratch (byte offsets). block 256 = 4 waves, tile 128(M) x 128(T), wave tile
// 64x64, mfma_f32_16x16x32_bf16, fragments loaded 16B/lane from global.
enum { EPI_PLAIN=0, EPI_RELU_SB=1, EPI_RES=2, EPI_LEAKY=3, EPI_CLS=4 };

template<int EPI, bool EXB>
__global__ __launch_bounds__(256) void gemm_tok(
    unsigned W0off, unsigned W1off, unsigned W2off,
    unsigned O0off, unsigned O1off, unsigned O2off,
    unsigned XoffB, int Xstride, int Xoff,
    int outStride, int outOff,
    const float* sPtr, const float* bPtr,
    const float* extraIn, unsigned extraOffB, int extraStride,
    unsigned resOffB, int resStride, int resOff,
    int K, int Astride)
{
  const unsigned short* X = (const unsigned short*)(g_scratch + XoffB);
  unsigned wOffB   = (blockIdx.z==0) ? W0off : ((blockIdx.z==1) ? W1off : W2off);
  unsigned outOffB = (blockIdx.z==0) ? O0off : ((blockIdx.z==1) ? O1off : O2off);
  const unsigned short* W = (const unsigned short*)(g_scratch + wOffB);
  unsigned short* out = (unsigned short*)(g_scratch + outOffB);
  int lane = threadIdx.x & 63, wave = threadIdx.x >> 6;
  int r = lane & 15, q = lane >> 4;
  int M0 = blockIdx.x*128 + (wave>>1)*64;
  int T0 = blockIdx.y*128 + (wave&1)*64;

  f32x4 acc[4][4];
  #pragma unroll
  for (int i=0;i<4;i++)
    #pragma unroll
    for (int j=0;j<4;j++)
      #pragma unroll
      for (int u=0;u<4;u++) acc[i][j][u] = 0.f;

  const unsigned short* Arow[4]; const unsigned short* Brow[4];
  #pragma unroll
  for (int i=0;i<4;i++) Arow[i] = W + (size_t)(M0 + i*16 + r)*Astride + q*8;
  #pragma unroll
  for (int j=0;j<4;j++) Brow[j] = X + (size_t)(T0 + j*16 + r)*Xstride + Xoff + q*8;

  for (int k0=0; k0<K; k0+=32){
    short8 a[4], bfr[4];
    #pragma unroll
    for (int i=0;i<4;i++) a[i]   = *(const short8*)(Arow[i] + k0);
    #pragma unroll
    for (int j=0;j<4;j++) bfr[j] = *(const short8*)(Brow[j] + k0);
    #pragma unroll
    for (int i=0;i<4;i++)
      #pragma unroll
      for (int j=0;j<4;j++)
        acc[i][j] = __builtin_amdgcn_mfma_f32_16x16x32_bf16(a[i], bfr[j], acc[i][j], 0, 0, 0);
  }

  // epilogue: D layout col=lane&15 (token), row=q*4+reg (channel)
  #pragma unroll
  for (int i=0;i<4;i++){
    int m = M0 + i*16 + q*4;
    float sv[4], bv[4];
    if constexpr (EPI != EPI_PLAIN){
      #pragma unroll
      for (int u=0;u<4;u++){ sv[u]=sPtr[m+u]; bv[u]=bPtr[m+u]; }
    }
    #pragma unroll
    for (int j=0;j<4;j++){
      int token = T0 + j*16 + r;
      float ex[4];
      if constexpr (EPI == EPI_CLS){
        int bb = token >> 12;
        #pragma unroll
        for (int u=0;u<4;u++)
          ex[u] = EXB ? extraIn[bb*extraStride + m + u]
                      : ((const float*)(g_scratch + extraOffB))[bb*extraStride + m + u];
      }
      float resv[4];
      if constexpr (EPI == EPI_RES){
        const unsigned short* resPtr = (const unsigned short*)(g_scratch + resOffB);
        ushort4v rv = *(const ushort4v*)(resPtr + (size_t)token*resStride + resOff + m);
        #pragma unroll
        for (int u=0;u<4;u++) resv[u]=bf2f(rv[u]);
      }
      ushort4v ov;
      #pragma unroll
      for (int u=0;u<4;u++){
        float a = acc[i][j][u];
        float vo;
        if constexpr (EPI == EPI_PLAIN)        vo = a;
        else if constexpr (EPI == EPI_RELU_SB) vo = fmaxf(sv[u]*a + bv[u], 0.f);
        else if constexpr (EPI == EPI_RES)     vo = resv[u] + fmaxf(sv[u]*a + bv[u], 0.f);
        else if constexpr (EPI == EPI_LEAKY){  float tt = sv[u]*a + bv[u]; vo = tt>0.f ? tt : 0.2f*tt; }
        else { /*EPI_CLS: relu(s*(acc+extra)+sh), bPtr=sh*/ vo = fmaxf(sv[u]*(a + ex[u]) + bv[u], 0.f); }
        ov[u] = f2bf(vo);
      }
      *(ushort4v*)(out + (size_t)token*outStride + outOff + m) = ov;
    }
  }
}

// ---------------- attention (one wave per query, 2 channels/lane) ----------------
__global__ __launch_bounds__(256) void attn_kernel(
  unsigned qOff, unsigned kOff, unsigned vOff, unsigned idxOff,
  const float* __restrict__ in, const float* __restrict__ wpos,
  unsigned aggOff)
{
  const unsigned short* Q  = (const unsigned short*)(g_scratch + qOff);
  const unsigned short* Kf = (const unsigned short*)(g_scratch + kOff);
  const unsigned short* V  = (const unsigned short*)(g_scratch + vOff);
  const int* idx           = (const int*)(g_scratch + idxOff);
  unsigned short* agg      = (unsigned short*)(g_scratch + aggOff);

  int lane = threadIdx.x & 63, wv = threadIdx.x >> 6;
  int t = blockIdx.x*4 + wv;
  int b = t >> 12, n = t & 4095;
  const float* xb = in + (size_t)b*9*NP;
  int c0 = lane*2;

  unsigned qv = *(const unsigned*)(Q + (size_t)t*128 + c0);
  float q0 = bf2f((unsigned short)(qv & 0xffff)), q1 = bf2f((unsigned short)(qv >> 16));
  float xn = xb[n], yn = xb[NP+n], zn = xb[2*NP+n];
  float wp00=wpos[c0*3+0],     wp01=wpos[c0*3+1],     wp02=wpos[c0*3+2];
  float wp10=wpos[(c0+1)*3+0], wp11=wpos[(c0+1)*3+1], wp12=wpos[(c0+1)*3+2];

  int mi[16]; float s[16];
  #pragma unroll
  for (int j=0;j<16;j++) mi[j] = idx[(size_t)t*16 + j] & 4095;  // mask: never OOB
  #pragma unroll
  for (int j=0;j<16;j++){
    unsigned kv = *(const unsigned*)(Kf + ((size_t)(b<<12) + mi[j])*128 + c0);
    float p = q0*bf2f((unsigned short)(kv & 0xffff)) + q1*bf2f((unsigned short)(kv >> 16));
    #pragma unroll
    for (int o=32;o>=1;o>>=1) p += __shfl_xor(p, o, 64);
    s[j] = p;
  }
  const float scale = 0.08838834764831845f; // 1/sqrt(128)
  float mx = s[0];
  #pragma unroll
  for (int j=1;j<16;j++) mx = fmaxf(mx, s[j]);
  float e[16], sum = 0.f;
  #pragma unroll
  for (int j=0;j<16;j++){ e[j] = __expf((s[j]-mx)*scale); sum += e[j]; }
  float inv = 1.f / sum;

  float a0=0.f, a1=0.f;
  #pragma unroll
  for (int j=0;j<16;j++){
    int m = mi[j];
    float w = e[j]*inv;
    unsigned vv = *(const unsigned*)(V + ((size_t)(b<<12) + m)*128 + c0);
    float rx = xn - xb[m];
    float ry = yn - xb[NP+m];
    float rz = zn - xb[2*NP+m];
    float p0 = wp00*rx + wp01*ry + wp02*rz;
    float p1 = wp10*rx + wp11*ry + wp12*rz;
    a0 += w*(bf2f((unsigned short)(vv & 0xffff)) + p0);
    a1 += w*(bf2f((unsigned short)(vv >> 16)) + p1);
  }
  unsigned pk = (unsigned)f2bf(a0) | ((unsigned)f2bf(a1) << 16);
  *(unsigned*)(agg + (size_t)t*128 + c0) = pk;
}

// ---------------- max/mean pool over tokens ----------------
// grid 64 (b*16 + cblk), block 256 = 64 channels x 4 token groups
__global__ __launch_bounds__(256) void pool_kernel(unsigned xfOff, unsigned gOff)
{
  const unsigned short* xf = (const unsigned short*)(g_scratch + xfOff);
  float* g = (float*)(g_scratch + gOff);
  int b = blockIdx.x >> 4, cblk = blockIdx.x & 15;
  int cl = threadIdx.x & 63, tg = threadIdx.x >> 6;
  int c = cblk*64 + cl;
  float mx = -3.0e38f, sm = 0.f;
  for (int n=tg; n<NP; n+=4){
    float v = bf2f(xf[((size_t)(b<<12) + n)*1024 + c]);
    mx = fmaxf(mx, v); sm += v;
  }
  __shared__ float smx[4][64], ssm[4][64];
  smx[tg][cl]=mx; ssm[tg][cl]=sm;
  __syncthreads();
  if (tg==0){
    #pragma unroll
    for (int k=1;k<4;k++){ mx = fmaxf(mx, smx[k][cl]); sm += ssm[k][cl]; }
    g[b*2048 + c] = mx;
    g[b*2048 + 1024 + c] = sm * (1.f/4096.f);
  }
}

// gb[b][o] = cls_bias1[o] + sum_c W1[o][1024+c]*g[b][c]  (fp32; grid 8 x 256)
__global__ __launch_bounds__(256) void gterm_kernel(const float* __restrict__ w1,
                                                    const float* __restrict__ bias1,
                                                    unsigned gOff, unsigned gbOff)
{
  const float* g = (const float*)(g_scratch + gOff);
  float* gb = (float*)(g_scratch + gbOff);
  int b = blockIdx.x >> 1;
  int o = (blockIdx.x & 1)*256 + threadIdx.x;
  const float* wrow = w1 + (size_t)o*3072 + 1024;
  const float* gp = g + b*2048;
  float acc = 0.f;
  for (int c=0;c<2048;c+=4){
    float4 wv4 = *(const float4*)(wrow + c);
    acc += wv4.x*gp[c] + wv4.y*gp[c+1] + wv4.z*gp[c+2] + wv4.w*gp[c+3];
  }
  gb[b*512 + o] = acc + bias1[o];
}

// ---------------- classifier head (O=13), fp32 out ----------------
// block 256 = 4 waves x (16 tokens x 4 c-quarters); grid 256.
__global__ __launch_bounds__(256) void cls3_kernel(unsigned c2Off,
                                                   const float* __restrict__ w3,
                                                   const float* __restrict__ bias3,
                                                   float* __restrict__ outp)
{
  const unsigned short* c2 = (const unsigned short*)(g_scratch + c2Off);
  __shared__ float wf[13*256];
  __shared__ float bf3[13];
  for (int i=threadIdx.x;i<13*256;i+=256) wf[i]=w3[i];
  if (threadIdx.x < 13) bf3[threadIdx.x]=bias3[threadIdx.x];
  __syncthreads();
  int lane = threadIdx.x & 63, wv = threadIdx.x >> 6;
  int tl = lane >> 2, cq = lane & 3;
  int t = blockIdx.x*64 + wv*16 + tl;
  const unsigned short* xrow = c2 + (size_t)t*256 + cq*64;
  float acc[13];
  #pragma unroll
  for (int o=0;o<13;o++) acc[o]=0.f;
  for (int c=0;c<64;c+=8){
    short8 xv = *(const short8*)(xrow + c);
    float xs[8];
    #pragma unroll
    for (int u=0;u<8;u++) xs[u]=bf2f((unsigned short)xv[u]);
    #pragma unroll
    for (int o=0;o<13;o++){
      const float* wr = wf + o*256 + cq*64 + c;
      #pragma unroll
      for (int u=0;u<8;u++) acc[o] += wr[u]*xs[u];
    }
  }
  #pragma unroll
  for (int o=0;o<13;o++){
    acc[o] += __shfl_xor(acc[o], 1, 64);
    acc[o] += __shfl_xor(acc[o], 2, 64);
  }
  if (cq==0){
    int b = t >> 12, n = t & 4095;
    #pragma unroll
    for (int o=0;o<13;o++)
      outp[((size_t)b*13 + o)*NP + n] = acc[o] + bf3[o];
  }
}

// ---------------- launch ----------------
extern "C" void kernel_launch(void* const* d_in, const int* in_sizes, int n_in,
                              void* d_out, int out_size, void* d_ws, size_t ws_size,
                              hipStream_t stream) {
  (void)in_sizes; (void)n_in; (void)out_size; (void)d_ws; (void)ws_size;
  const float* in      = (const float*)d_in[0];
  const float* emb_w1  = (const float*)d_in[1];
  const float* emb_s1  = (const float*)d_in[2];
  const float* emb_b1  = (const float*)d_in[3];
  const float* emb_w2  = (const float*)d_in[4];
  const float* emb_s2  = (const float*)d_in[5];
  const float* emb_b2  = (const float*)d_in[6];
  const float* blk_wq  = (const float*)d_in[7];
  const float* blk_wk  = (const float*)d_in[8];
  const float* blk_wv  = (const float*)d_in[9];
  const float* blk_wpos= (const float*)d_in[10];
  const float* blk_wo  = (const float*)d_in[11];
  const float* blk_s   = (const float*)d_in[12];
  const float* blk_b   = (const float*)d_in[13];
  const float* fuse_w  = (const float*)d_in[14];
  const float* fuse_s  = (const float*)d_in[15];
  const float* fuse_b  = (const float*)d_in[16];
  const float* cls_w1  = (const float*)d_in[17];
  const float* cls_b1  = (const float*)d_in[18];
  const float* cls_s1  = (const float*)d_in[19];
  const float* cls_sh1 = (const float*)d_in[20];
  const float* cls_w2  = (const float*)d_in[21];
  const float* cls_b2  = (const float*)d_in[22];
  const float* cls_s2  = (const float*)d_in[23];
  const float* cls_sh2 = (const float*)d_in[24];
  const float* cls_w3  = (const float*)d_in[25];
  const float* cls_b3  = (const float*)d_in[26];

  // byte offsets into g_scratch (non-aliased; total 106 MB of 112 MB)
  const unsigned MB = 1u<<20, KB = 1024u;
  const unsigned OFF_IDX   = 0;                 // 1 MB   int idx[T][16]
  const unsigned OFF_WQ    = 1*MB;              // 96 KB  bf16 (3,128,128)
  const unsigned OFF_WK    = 1*MB + 128*KB;     // 96 KB
  const unsigned OFF_WV    = 1*MB + 256*KB;     // 96 KB
  const unsigned OFF_WO    = 1*MB + 384*KB;     // 96 KB
  const unsigned OFF_WEMB2 = 1*MB + 512*KB;     // 32 KB  bf16 (128,128)
  const unsigned OFF_WFUSE = 1*MB + 576*KB;     // 768 KB bf16 (1024,384)
  const unsigned OFF_WW1   = 3*MB;              // 1 MB   bf16 (512,1024) x-half
  const unsigned OFF_WW2   = 4*MB;              // 256 KB bf16 (256,512)
  const unsigned OFF_X1    = 5*MB;              // 4 MB   bf16 (T,128)
  const unsigned OFF_X0    = 9*MB;              // 4 MB   bf16 (T,128)
  const unsigned OFF_XCAT  = 13*MB;             // 12 MB  bf16 (T,384)
  const unsigned OFF_QB    = 25*MB;             // 4 MB
  const unsigned OFF_KB    = 29*MB;             // 4 MB
  const unsigned OFF_VB    = 33*MB;             // 4 MB
  const unsigned OFF_AGG   = 37*MB;             // 4 MB
  const unsigned OFF_XF    = 41*MB;             // 32 MB  bf16 (T,1024)
  const unsigned OFF_C1    = 73*MB;             // 16 MB  bf16 (T,512)
  const unsigned OFF_C2    = 89*MB;             // 8 MB   bf16 (T,256)
  const unsigned OFF_G     = 97*MB;             // 32 KB  f32 (B,2048)
  const unsigned OFF_GB    = 97*MB + 64*KB;     // 8 KB   f32 (B,512)
  const unsigned OFF_PD    = 98*MB;             // 4 MB   f32 knn partial dist
  const unsigned OFF_PI    = 102*MB;            // 4 MB   int knn partial idx
  float* outp = (float*)d_out;                  // (B,13,N) f32

  // 0: weight conversion prepass (fp32 -> bf16 into scratch)
  cvt_flat<<<dim3(64), 256, 0, stream>>>(emb_w2, OFF_WEMB2, 128*128);
  cvt_flat<<<dim3(192), 256, 0, stream>>>(blk_wq, OFF_WQ, 3*128*128);
  cvt_flat<<<dim3(192), 256, 0, stream>>>(blk_wk, OFF_WK, 3*128*128);
  cvt_flat<<<dim3(192), 256, 0, stream>>>(blk_wv, OFF_WV, 3*128*128);
  cvt_flat<<<dim3(192), 256, 0, stream>>>(blk_wo, OFF_WO, 3*128*128);
  cvt_flat<<<dim3(256), 256, 0, stream>>>(fuse_w, OFF_WFUSE, 1024*384);
  cvt_pitch1024<<<dim3(256), 256, 0, stream>>>(cls_w1, OFF_WW1, 512*1024);
  cvt_flat<<<dim3(256), 256, 0, stream>>>(cls_w2, OFF_WW2, 256*512);

  // 1-2: KNN
  knn_scan<<<dim3(16,4,4), 256, 0, stream>>>(in, OFF_PD, OFF_PI);
  knn_merge<<<dim3(64), 256, 0, stream>>>(OFF_PD, OFF_PI, OFF_IDX);
  // 3-4: embedding
  emb1_kernel<<<dim3(64), 256, 0, stream>>>(in, emb_w1, emb_s1, emb_b1, OFF_X1);
  gemm_tok<EPI_RELU_SB,false><<<dim3(1,128,1), 256, 0, stream>>>(
      OFF_WEMB2, OFF_WEMB2, OFF_WEMB2, OFF_X0, OFF_X0, OFF_X0,
      OFF_X1, 128, 0, 128, 0, emb_s2, emb_b2,
      nullptr, 0, 0, 0, 0, 0, 128, 128);
  // 5-7: transformer blocks
  for (int i=0;i<3;i++){
    unsigned wq = OFF_WQ + i*32768, wk = OFF_WK + i*32768;
    unsigned wv = OFF_WV + i*32768, wo = OFF_WO + i*32768;
    const float* wp = blk_wpos + i*128*3;
    const float* si = blk_s + i*128;
    const float* bi = blk_b + i*128;
    unsigned XiOff = (i==0) ? OFF_X0 : OFF_XCAT;
    int Xs = (i==0) ? 128 : 384;
    int Xo = (i==0) ? 0 : (i-1)*128;
    gemm_tok<EPI_PLAIN,false><<<dim3(1,128,3), 256, 0, stream>>>(
        wq, wk, wv, OFF_QB, OFF_KB, OFF_VB,
        XiOff, Xs, Xo, 128, 0, nullptr, nullptr,
        nullptr, 0, 0, 0, 0, 0, 128, 128);
    attn_kernel<<<dim3(4096), 256, 0, stream>>>(OFF_QB, OFF_KB, OFF_VB, OFF_IDX, in, wp, OFF_AGG);
    gemm_tok<EPI_RES,false><<<dim3(1,128,1), 256, 0, stream>>>(
        wo, wo, wo, OFF_XCAT, OFF_XCAT, OFF_XCAT,
        OFF_AGG, 128, 0, 384, i*128, si, bi,
        nullptr, 0, 0, XiOff, Xs, Xo, 128, 128);
  }
  // 8: fuse (leaky relu)
  gemm_tok<EPI_LEAKY,false><<<dim3(8,128,1), 256, 0, stream>>>(
      OFF_WFUSE, OFF_WFUSE, OFF_WFUSE, OFF_XF, OFF_XF, OFF_XF,
      OFF_XCAT, 384, 0, 1024, 0, fuse_s, fuse_b,
      nullptr, 0, 0, 0, 0, 0, 384, 384);
  // 9-10: pooling + broadcast-g term of cls1 (fp32, exactish)
  pool_kernel<<<dim3(64), 256, 0, stream>>>(OFF_XF, OFF_G);
  gterm_kernel<<<dim3(8), 256, 0, stream>>>(cls_w1, cls_b1, OFF_G, OFF_GB);
  // 11: cls1 (K=1024 x-half of W1; gb = W1[:,1024:]@g + bias1 as extra)
  gemm_tok<EPI_CLS,false><<<dim3(4,128,1), 256, 0, stream>>>(
      OFF_WW1, OFF_WW1, OFF_WW1, OFF_C1, OFF_C1, OFF_C1,
      OFF_XF, 1024, 0, 512, 0, cls_s1, cls_sh1,
      nullptr, OFF_GB, 512, 0, 0, 0, 1024, 1024);
  // 12: cls2
  gemm_tok<EPI_CLS,true><<<dim3(2,128,1), 256, 0, stream>>>(
      OFF_WW2, OFF_WW2, OFF_WW2, OFF_C2, OFF_C2, OFF_C2,
      OFF_C1, 512, 0, 256, 0, cls_s2, cls_sh2,
      cls_b2, 0, 0, 0, 0, 0, 512, 512);
  // 13: cls3 -> d_out (fp32)
  cls3_kernel<<<dim3(256), 256, 0, stream>>>(OFF_C2, cls_w3, cls_b3, outp);
}

// Round 5
// 1138.553 us; speedup vs baseline: 1.3729x; 1.3729x over previous
//
#include <hip/hip_runtime.h>

// PVDST semseg, MI355X/gfx950. I/O dtype FP32. Round-4: KNN rework.
//   - knn_scan was 49% of runtime: 1 block/CU (11% occupancy) + serial
//     16-deep swap chain in insert16 (dep-bound, VALUBusy 64%).
//   - Now: branchless predicated sorted-insert (depth ~2, no exec branches)
//     + 16 candidate chunks -> 1024 blocks (4/CU, 50% occupancy).
//   - merge: 16 sorted lists/query, early-break + branchless insert.
// Rest of pipeline unchanged from round 3 (passed, absmax 2.9e-3).

#define NB 4
#define NP 4096
#define NT 16384   // NB*NP tokens

#define SCRATCH_BYTES (132u*1024u*1024u)
__device__ __align__(256) unsigned char g_scratch[SCRATCH_BYTES];

typedef __attribute__((ext_vector_type(8))) short short8;   // 8 x bf16 MFMA frag
typedef __attribute__((ext_vector_type(4))) float f32x4;    // MFMA acc
typedef __attribute__((ext_vector_type(4))) unsigned short ushort4v;

__device__ __forceinline__ float bf2f(unsigned short u){
  unsigned int v = ((unsigned int)u) << 16;
  return __builtin_bit_cast(float, v);
}
__device__ __forceinline__ unsigned short f2bf(float f){
  unsigned int x = __builtin_bit_cast(unsigned int, f);
  x += 0x7fffu + ((x >> 16) & 1u);     // RNE
  return (unsigned short)(x >> 16);
}
// numpy-matched: ((x*x)+(y*y))+(z*z), each op rounded (no fma contraction)
__device__ __forceinline__ float sq3(float x, float y, float z){
  return __fadd_rn(__fadd_rn(__fmul_rn(x,x), __fmul_rn(y,y)), __fmul_rn(z,z));
}

// Branchless sorted-ascending top-16 insert. Strict < => incumbent (earlier
// index) wins ties, matching stable top_k with ascending-index scan order.
// 16 independent cmps + 64 cndmasks, dep depth ~2 (vs serial swap chain).
__device__ __forceinline__ void bl_insert16(float (&dist)[16], int (&ind)[16], float d, int m){
  bool c[16];
  #pragma unroll
  for (int j=0;j<16;j++) c[j] = d < dist[j];
  #pragma unroll
  for (int j=15;j>=1;--j){
    dist[j] = c[j-1] ? dist[j-1] : (c[j] ? d : dist[j]);
    ind[j]  = c[j-1] ? ind[j-1]  : (c[j] ? m : ind[j]);
  }
  dist[0] = c[0] ? d : dist[0];
  ind[0]  = c[0] ? m : ind[0];
}

// ---------------- weight fp32 -> bf16 conversion prepass ----------------
__global__ __launch_bounds__(256) void cvt_flat(const float* __restrict__ src,
                                                unsigned dstOff, int n)
{
  unsigned short* dst = (unsigned short*)(g_scratch + dstOff);
  for (int i = blockIdx.x*256 + threadIdx.x; i < n; i += gridDim.x*256)
    dst[i] = f2bf(src[i]);
}
// cls_w1 x-half: rows x 1024 cols out of pitch-3072 rows
__global__ __launch_bounds__(256) void cvt_pitch1024(const float* __restrict__ src,
                                                     unsigned dstOff, int n /*rows<<10*/)
{
  unsigned short* dst = (unsigned short*)(g_scratch + dstOff);
  for (int i = blockIdx.x*256 + threadIdx.x; i < n; i += gridDim.x*256){
    int r = i >> 10, c = i & 1023;
    dst[i] = f2bf(src[(size_t)r*3072 + c]);
  }
}

// ---------------- KNN (exact fp32) ----------------
// grid (16 qchunks, 16 cchunks, B), block 256. One thread = one query vs 256
// candidates staged in LDS as float4(x,y,z,sq). 1024 blocks -> 4/CU.
__global__ __launch_bounds__(256) void knn_scan(const float* __restrict__ in,
                                                unsigned pdOff, unsigned piOff)
{
  float* pdist = (float*)(g_scratch + pdOff);
  int*   pidx  = (int*)  (g_scratch + piOff);
  __shared__ float4 sp[256];
  int b = blockIdx.z, qc = blockIdx.x, cc = blockIdx.y;
  const float* xb = in + (size_t)b*9*NP;
  int base = cc*256;
  {
    int i = threadIdx.x;
    float x = xb[base+i], y = xb[NP+base+i], z = xb[2*NP+base+i];
    sp[i] = make_float4(x,y,z,sq3(x,y,z));
  }
  __syncthreads();
  int n = qc*256 + threadIdx.x;
  float xn=xb[n], yn=xb[NP+n], zn=xb[2*NP+n];
  float sqn = sq3(xn,yn,zn);
  float dist[16]; int ind[16];
  #pragma unroll
  for (int j=0;j<16;j++){ dist[j]=3.0e38f; ind[j]=0; }
  for (int mm=0; mm<256; ++mm){
    float4 p = sp[mm];
    float dot = __fadd_rn(__fadd_rn(__fmul_rn(xn,p.x), __fmul_rn(yn,p.y)), __fmul_rn(zn,p.z));
    float d = __fsub_rn(__fadd_rn(sqn, p.w), __fmul_rn(2.0f, dot));
    bl_insert16(dist, ind, d, base+mm);
  }
  size_t o = ((size_t)((b*16 + cc)*NP + n))*16;
  #pragma unroll
  for (int j=0;j<16;j++){ pdist[o+j]=dist[j]; pidx[o+j]=ind[j]; }
}

// grid 128 x 128: merge 16 sorted chunk lists (ascending index order across
// chunks => strict < keeps stable tie-breaking). Early-break: a sorted list
// whose next element >= current kth cannot contribute further.
__global__ __launch_bounds__(128) void knn_merge(unsigned pdOff, unsigned piOff, unsigned idxOff)
{
  const float* pdist = (const float*)(g_scratch + pdOff);
  const int*   pidx  = (const int*)  (g_scratch + piOff);
  int*         idxOut= (int*)        (g_scratch + idxOff);
  int t = blockIdx.x*128 + threadIdx.x;
  int b = t >> 12, n = t & 4095;
  float dist[16]; int ind[16];
  #pragma unroll
  for (int j=0;j<16;j++){ dist[j]=3.0e38f; ind[j]=0; }
  for (int cc=0; cc<16; ++cc){
    size_t o = ((size_t)((b*16 + cc)*NP + n))*16;
    for (int j=0;j<16;j++){
      float pd = pdist[o+j];
      if (pd >= dist[15]) break;          // sorted list: rest can't insert
      bl_insert16(dist, ind, pd, pidx[o+j]);
    }
  }
  #pragma unroll
  for (int j=0;j<16;j++) idxOut[t*16+j] = ind[j];
}

// ---------------- embedding conv1 (Cin=9), fp32 in -> bf16 out ----------------
__global__ __launch_bounds__(256) void emb1_kernel(const float* __restrict__ in,
                                                   const float* __restrict__ w1,
                                                   const float* __restrict__ s1,
                                                   const float* __restrict__ b1,
                                                   unsigned x1Off)
{
  unsigned short* x1 = (unsigned short*)(g_scratch + x1Off);
  __shared__ float wf[128*9], sf[128], bf_[128];
  for (int i=threadIdx.x;i<128*9;i+=256) wf[i]=w1[i];
  if (threadIdx.x < 128){ sf[threadIdx.x]=s1[threadIdx.x]; bf_[threadIdx.x]=b1[threadIdx.x]; }
  __syncthreads();
  int t = blockIdx.x*256 + threadIdx.x;
  int b = t >> 12, n = t & 4095;
  float v[9];
  #pragma unroll
  for (int c=0;c<9;c++) v[c] = in[((size_t)b*9 + c)*NP + n];
  for (int o=0;o<128;o+=2){
    float a0=0.f, a1=0.f;
    #pragma unroll
    for (int c=0;c<9;c++){ a0 += wf[o*9+c]*v[c]; a1 += wf[(o+1)*9+c]*v[c]; }
    a0 = fmaxf(sf[o]*a0 + bf_[o], 0.f);
    a1 = fmaxf(sf[o+1]*a1 + bf_[o+1], 0.f);
    unsigned pk = (unsigned)f2bf(a0) | ((unsigned)f2bf(a1) << 16);
    *(unsigned*)(x1 + (size_t)t*128 + o) = pk;
  }
}

// ---------------- generic token-major MFMA GEMM (bf16 in/out) ----------------
// out[token][m] = epi( sum_k W[m][k] * X[token][k] ); W and X are bf16 in
// scratch (byte offsets). block 256 = 4 waves, tile 128(M) x 128(T), wave tile
// 64x64, mfma_f32_16x16x32_bf16, fragments loaded 16B/lane from global.
enum { EPI_PLAIN=0, EPI_RELU_SB=1, EPI_RES=2, EPI_LEAKY=3, EPI_CLS=4 };

template<int EPI, bool EXB>
__global__ __launch_bounds__(256) void gemm_tok(
    unsigned W0off, unsigned W1off, unsigned W2off,
    unsigned O0off, unsigned O1off, unsigned O2off,
    unsigned XoffB, int Xstride, int Xoff,
    int outStride, int outOff,
    const float* sPtr, const float* bPtr,
    const float* extraIn, unsigned extraOffB, int extraStride,
    unsigned resOffB, int resStride, int resOff,
    int K, int Astride)
{
  const unsigned short* X = (const unsigned short*)(g_scratch + XoffB);
  unsigned wOffB   = (blockIdx.z==0) ? W0off : ((blockIdx.z==1) ? W1off : W2off);
  unsigned outOffB = (blockIdx.z==0) ? O0off : ((blockIdx.z==1) ? O1off : O2off);
  const unsigned short* W = (const unsigned short*)(g_scratch + wOffB);
  unsigned short* out = (unsigned short*)(g_scratch + outOffB);
  int lane = threadIdx.x & 63, wave = threadIdx.x >> 6;
  int r = lane & 15, q = lane >> 4;
  int M0 = blockIdx.x*128 + (wave>>1)*64;
  int T0 = blockIdx.y*128 + (wave&1)*64;

  f32x4 acc[4][4];
  #pragma unroll
  for (int i=0;i<4;i++)
    #pragma unroll
    for (int j=0;j<4;j++)
      #pragma unroll
      for (int u=0;u<4;u++) acc[i][j][u] = 0.f;

  const unsigned short* Arow[4]; const unsigned short* Brow[4];
  #pragma unroll
  for (int i=0;i<4;i++) Arow[i] = W + (size_t)(M0 + i*16 + r)*Astride + q*8;
  #pragma unroll
  for (int j=0;j<4;j++) Brow[j] = X + (size_t)(T0 + j*16 + r)*Xstride + Xoff + q*8;

  for (int k0=0; k0<K; k0+=32){
    short8 a[4], bfr[4];
    #pragma unroll
    for (int i=0;i<4;i++) a[i]   = *(const short8*)(Arow[i] + k0);
    #pragma unroll
    for (int j=0;j<4;j++) bfr[j] = *(const short8*)(Brow[j] + k0);
    #pragma unroll
    for (int i=0;i<4;i++)
      #pragma unroll
      for (int j=0;j<4;j++)
        acc[i][j] = __builtin_amdgcn_mfma_f32_16x16x32_bf16(a[i], bfr[j], acc[i][j], 0, 0, 0);
  }

  // epilogue: D layout col=lane&15 (token), row=q*4+reg (channel)
  #pragma unroll
  for (int i=0;i<4;i++){
    int m = M0 + i*16 + q*4;
    float sv[4], bv[4];
    if constexpr (EPI != EPI_PLAIN){
      #pragma unroll
      for (int u=0;u<4;u++){ sv[u]=sPtr[m+u]; bv[u]=bPtr[m+u]; }
    }
    #pragma unroll
    for (int j=0;j<4;j++){
      int token = T0 + j*16 + r;
      float ex[4];
      if constexpr (EPI == EPI_CLS){
        int bb = token >> 12;
        #pragma unroll
        for (int u=0;u<4;u++)
          ex[u] = EXB ? extraIn[bb*extraStride + m + u]
                      : ((const float*)(g_scratch + extraOffB))[bb*extraStride + m + u];
      }
      float resv[4];
      if constexpr (EPI == EPI_RES){
        const unsigned short* resPtr = (const unsigned short*)(g_scratch + resOffB);
        ushort4v rv = *(const ushort4v*)(resPtr + (size_t)token*resStride + resOff + m);
        #pragma unroll
        for (int u=0;u<4;u++) resv[u]=bf2f(rv[u]);
      }
      ushort4v ov;
      #pragma unroll
      for (int u=0;u<4;u++){
        float a = acc[i][j][u];
        float vo;
        if constexpr (EPI == EPI_PLAIN)        vo = a;
        else if constexpr (EPI == EPI_RELU_SB) vo = fmaxf(sv[u]*a + bv[u], 0.f);
        else if constexpr (EPI == EPI_RES)     vo = resv[u] + fmaxf(sv[u]*a + bv[u], 0.f);
        else if constexpr (EPI == EPI_LEAKY){  float tt = sv[u]*a + bv[u]; vo = tt>0.f ? tt : 0.2f*tt; }
        else { /*EPI_CLS: relu(s*(acc+extra)+sh), bPtr=sh*/ vo = fmaxf(sv[u]*(a + ex[u]) + bv[u], 0.f); }
        ov[u] = f2bf(vo);
      }
      *(ushort4v*)(out + (size_t)token*outStride + outOff + m) = ov;
    }
  }
}

// ---------------- attention (one wave per query, 2 channels/lane) ----------------
__global__ __launch_bounds__(256) void attn_kernel(
  unsigned qOff, unsigned kOff, unsigned vOff, unsigned idxOff,
  const float* __restrict__ in, const float* __restrict__ wpos,
  unsigned aggOff)
{
  const unsigned short* Q  = (const unsigned short*)(g_scratch + qOff);
  const unsigned short* Kf = (const unsigned short*)(g_scratch + kOff);
  const unsigned short* V  = (const unsigned short*)(g_scratch + vOff);
  const int* idx           = (const int*)(g_scratch + idxOff);
  unsigned short* agg      = (unsigned short*)(g_scratch + aggOff);

  int lane = threadIdx.x & 63, wv = threadIdx.x >> 6;
  int t = blockIdx.x*4 + wv;
  int b = t >> 12, n = t & 4095;
  const float* xb = in + (size_t)b*9*NP;
  int c0 = lane*2;

  unsigned qv = *(const unsigned*)(Q + (size_t)t*128 + c0);
  float q0 = bf2f((unsigned short)(qv & 0xffff)), q1 = bf2f((unsigned short)(qv >> 16));
  float xn = xb[n], yn = xb[NP+n], zn = xb[2*NP+n];
  float wp00=wpos[c0*3+0],     wp01=wpos[c0*3+1],     wp02=wpos[c0*3+2];
  float wp10=wpos[(c0+1)*3+0], wp11=wpos[(c0+1)*3+1], wp12=wpos[(c0+1)*3+2];

  int mi[16]; float s[16];
  #pragma unroll
  for (int j=0;j<16;j++) mi[j] = idx[(size_t)t*16 + j] & 4095;  // mask: never OOB
  #pragma unroll
  for (int j=0;j<16;j++){
    unsigned kv = *(const unsigned*)(Kf + ((size_t)(b<<12) + mi[j])*128 + c0);
    float p = q0*bf2f((unsigned short)(kv & 0xffff)) + q1*bf2f((unsigned short)(kv >> 16));
    #pragma unroll
    for (int o=32;o>=1;o>>=1) p += __shfl_xor(p, o, 64);
    s[j] = p;
  }
  const float scale = 0.08838834764831845f; // 1/sqrt(128)
  float mx = s[0];
  #pragma unroll
  for (int j=1;j<16;j++) mx = fmaxf(mx, s[j]);
  float e[16], sum = 0.f;
  #pragma unroll
  for (int j=0;j<16;j++){ e[j] = __expf((s[j]-mx)*scale); sum += e[j]; }
  float inv = 1.f / sum;

  float a0=0.f, a1=0.f;
  #pragma unroll
  for (int j=0;j<16;j++){
    int m = mi[j];
    float w = e[j]*inv;
    unsigned vv = *(const unsigned*)(V + ((size_t)(b<<12) + m)*128 + c0);
    float rx = xn - xb[m];
    float ry = yn - xb[NP+m];
    float rz = zn - xb[2*NP+m];
    float p0 = wp00*rx + wp01*ry + wp02*rz;
    float p1 = wp10*rx + wp11*ry + wp12*rz;
    a0 += w*(bf2f((unsigned short)(vv & 0xffff)) + p0);
    a1 += w*(bf2f((unsigned short)(vv >> 16)) + p1);
  }
  unsigned pk = (unsigned)f2bf(a0) | ((unsigned)f2bf(a1) << 16);
  *(unsigned*)(agg + (size_t)t*128 + c0) = pk;
}

// ---------------- max/mean pool over tokens ----------------
// grid 64 (b*16 + cblk), block 256 = 64 channels x 4 token groups
__global__ __launch_bounds__(256) void pool_kernel(unsigned xfOff, unsigned gOff)
{
  const unsigned short* xf = (const unsigned short*)(g_scratch + xfOff);
  float* g = (float*)(g_scratch + gOff);
  int b = blockIdx.x >> 4, cblk = blockIdx.x & 15;
  int cl = threadIdx.x & 63, tg = threadIdx.x >> 6;
  int c = cblk*64 + cl;
  float mx = -3.0e38f, sm = 0.f;
  for (int n=tg; n<NP; n+=4){
    float v = bf2f(xf[((size_t)(b<<12) + n)*1024 + c]);
    mx = fmaxf(mx, v); sm += v;
  }
  __shared__ float smx[4][64], ssm[4][64];
  smx[tg][cl]=mx; ssm[tg][cl]=sm;
  __syncthreads();
  if (tg==0){
    #pragma unroll
    for (int k=1;k<4;k++){ mx = fmaxf(mx, smx[k][cl]); sm += ssm[k][cl]; }
    g[b*2048 + c] = mx;
    g[b*2048 + 1024 + c] = sm * (1.f/4096.f);
  }
}

// gb[b][o] = cls_bias1[o] + sum_c W1[o][1024+c]*g[b][c]  (fp32; grid 8 x 256)
__global__ __launch_bounds__(256) void gterm_kernel(const float* __restrict__ w1,
                                                    const float* __restrict__ bias1,
                                                    unsigned gOff, unsigned gbOff)
{
  const float* g = (const float*)(g_scratch + gOff);
  float* gb = (float*)(g_scratch + gbOff);
  int b = blockIdx.x >> 1;
  int o = (blockIdx.x & 1)*256 + threadIdx.x;
  const float* wrow = w1 + (size_t)o*3072 + 1024;
  const float* gp = g + b*2048;
  float acc = 0.f;
  for (int c=0;c<2048;c+=4){
    float4 wv4 = *(const float4*)(wrow + c);
    acc += wv4.x*gp[c] + wv4.y*gp[c+1] + wv4.z*gp[c+2] + wv4.w*gp[c+3];
  }
  gb[b*512 + o] = acc + bias1[o];
}

// ---------------- classifier head (O=13), fp32 out ----------------
// block 256 = 4 waves x (16 tokens x 4 c-quarters); grid 256.
__global__ __launch_bounds__(256) void cls3_kernel(unsigned c2Off,
                                                   const float* __restrict__ w3,
                                                   const float* __restrict__ bias3,
                                                   float* __restrict__ outp)
{
  const unsigned short* c2 = (const unsigned short*)(g_scratch + c2Off);
  __shared__ float wf[13*256];
  __shared__ float bf3[13];
  for (int i=threadIdx.x;i<13*256;i+=256) wf[i]=w3[i];
  if (threadIdx.x < 13) bf3[threadIdx.x]=bias3[threadIdx.x];
  __syncthreads();
  int lane = threadIdx.x & 63, wv = threadIdx.x >> 6;
  int tl = lane >> 2, cq = lane & 3;
  int t = blockIdx.x*64 + wv*16 + tl;
  const unsigned short* xrow = c2 + (size_t)t*256 + cq*64;
  float acc[13];
  #pragma unroll
  for (int o=0;o<13;o++) acc[o]=0.f;
  for (int c=0;c<64;c+=8){
    short8 xv = *(const short8*)(xrow + c);
    float xs[8];
    #pragma unroll
    for (int u=0;u<8;u++) xs[u]=bf2f((unsigned short)xv[u]);
    #pragma unroll
    for (int o=0;o<13;o++){
      const float* wr = wf + o*256 + cq*64 + c;
      #pragma unroll
      for (int u=0;u<8;u++) acc[o] += wr[u]*xs[u];
    }
  }
  #pragma unroll
  for (int o=0;o<13;o++){
    acc[o] += __shfl_xor(acc[o], 1, 64);
    acc[o] += __shfl_xor(acc[o], 2, 64);
  }
  if (cq==0){
    int b = t >> 12, n = t & 4095;
    #pragma unroll
    for (int o=0;o<13;o++)
      outp[((size_t)b*13 + o)*NP + n] = acc[o] + bf3[o];
  }
}

// ---------------- launch ----------------
extern "C" void kernel_launch(void* const* d_in, const int* in_sizes, int n_in,
                              void* d_out, int out_size, void* d_ws, size_t ws_size,
                              hipStream_t stream) {
  (void)in_sizes; (void)n_in; (void)out_size; (void)d_ws; (void)ws_size;
  const float* in      = (const float*)d_in[0];
  const float* emb_w1  = (const float*)d_in[1];
  const float* emb_s1  = (const float*)d_in[2];
  const float* emb_b1  = (const float*)d_in[3];
  const float* emb_w2  = (const float*)d_in[4];
  const float* emb_s2  = (const float*)d_in[5];
  const float* emb_b2  = (const float*)d_in[6];
  const float* blk_wq  = (const float*)d_in[7];
  const float* blk_wk  = (const float*)d_in[8];
  const float* blk_wv  = (const float*)d_in[9];
  const float* blk_wpos= (const float*)d_in[10];
  const float* blk_wo  = (const float*)d_in[11];
  const float* blk_s   = (const float*)d_in[12];
  const float* blk_b   = (const float*)d_in[13];
  const float* fuse_w  = (const float*)d_in[14];
  const float* fuse_s  = (const float*)d_in[15];
  const float* fuse_b  = (const float*)d_in[16];
  const float* cls_w1  = (const float*)d_in[17];
  const float* cls_b1  = (const float*)d_in[18];
  const float* cls_s1  = (const float*)d_in[19];
  const float* cls_sh1 = (const float*)d_in[20];
  const float* cls_w2  = (const float*)d_in[21];
  const float* cls_b2  = (const float*)d_in[22];
  const float* cls_s2  = (const float*)d_in[23];
  const float* cls_sh2 = (const float*)d_in[24];
  const float* cls_w3  = (const float*)d_in[25];
  const float* cls_b3  = (const float*)d_in[26];

  // byte offsets into g_scratch (non-aliased)
  const unsigned MB = 1u<<20, KB = 1024u;
  const unsigned OFF_IDX   = 0;                 // 1 MB   int idx[T][16]
  const unsigned OFF_WQ    = 1*MB;              // 96 KB  bf16 (3,128,128)
  const unsigned OFF_WK    = 1*MB + 128*KB;     // 96 KB
  const unsigned OFF_WV    = 1*MB + 256*KB;     // 96 KB
  const unsigned OFF_WO    = 1*MB + 384*KB;     // 96 KB
  const unsigned OFF_WEMB2 = 1*MB + 512*KB;     // 32 KB  bf16 (128,128)
  const unsigned OFF_WFUSE = 1*MB + 576*KB;     // 768 KB bf16 (1024,384)
  const unsigned OFF_WW1   = 3*MB;              // 1 MB   bf16 (512,1024) x-half
  const unsigned OFF_WW2   = 4*MB;              // 256 KB bf16 (256,512)
  const unsigned OFF_X1    = 5*MB;              // 4 MB   bf16 (T,128)
  const unsigned OFF_X0    = 9*MB;              // 4 MB   bf16 (T,128)
  const unsigned OFF_XCAT  = 13*MB;             // 12 MB  bf16 (T,384)
  const unsigned OFF_QB    = 25*MB;             // 4 MB
  const unsigned OFF_KB    = 29*MB;             // 4 MB
  const unsigned OFF_VB    = 33*MB;             // 4 MB
  const unsigned OFF_AGG   = 37*MB;             // 4 MB
  const unsigned OFF_XF    = 41*MB;             // 32 MB  bf16 (T,1024)
  const unsigned OFF_C1    = 73*MB;             // 16 MB  bf16 (T,512)
  const unsigned OFF_C2    = 89*MB;             // 8 MB   bf16 (T,256)
  const unsigned OFF_G     = 97*MB;             // 32 KB  f32 (B,2048)
  const unsigned OFF_GB    = 97*MB + 64*KB;     // 8 KB   f32 (B,512)
  const unsigned OFF_PD    = 98*MB;             // 16 MB  f32 knn partial dist (B,16,NP,16)
  const unsigned OFF_PI    = 114*MB;            // 16 MB  int knn partial idx
  float* outp = (float*)d_out;                  // (B,13,N) f32

  // 0: weight conversion prepass (fp32 -> bf16 into scratch)
  cvt_flat<<<dim3(64), 256, 0, stream>>>(emb_w2, OFF_WEMB2, 128*128);
  cvt_flat<<<dim3(192), 256, 0, stream>>>(blk_wq, OFF_WQ, 3*128*128);
  cvt_flat<<<dim3(192), 256, 0, stream>>>(blk_wk, OFF_WK, 3*128*128);
  cvt_flat<<<dim3(192), 256, 0, stream>>>(blk_wv, OFF_WV, 3*128*128);
  cvt_flat<<<dim3(192), 256, 0, stream>>>(blk_wo, OFF_WO, 3*128*128);
  cvt_flat<<<dim3(256), 256, 0, stream>>>(fuse_w, OFF_WFUSE, 1024*384);
  cvt_pitch1024<<<dim3(256), 256, 0, stream>>>(cls_w1, OFF_WW1, 512*1024);
  cvt_flat<<<dim3(256), 256, 0, stream>>>(cls_w2, OFF_WW2, 256*512);

  // 1-2: KNN
  knn_scan<<<dim3(16,16,4), 256, 0, stream>>>(in, OFF_PD, OFF_PI);
  knn_merge<<<dim3(128), 128, 0, stream>>>(OFF_PD, OFF_PI, OFF_IDX);
  // 3-4: embedding
  emb1_kernel<<<dim3(64), 256, 0, stream>>>(in, emb_w1, emb_s1, emb_b1, OFF_X1);
  gemm_tok<EPI_RELU_SB,false><<<dim3(1,128,1), 256, 0, stream>>>(
      OFF_WEMB2, OFF_WEMB2, OFF_WEMB2, OFF_X0, OFF_X0, OFF_X0,
      OFF_X1, 128, 0, 128, 0, emb_s2, emb_b2,
      nullptr, 0, 0, 0, 0, 0, 128, 128);
  // 5-7: transformer blocks
  for (int i=0;i<3;i++){
    unsigned wq = OFF_WQ + i*32768, wk = OFF_WK + i*32768;
    unsigned wv = OFF_WV + i*32768, wo = OFF_WO + i*32768;
    const float* wp = blk_wpos + i*128*3;
    const float* si = blk_s + i*128;
    const float* bi = blk_b + i*128;
    unsigned XiOff = (i==0) ? OFF_X0 : OFF_XCAT;
    int Xs = (i==0) ? 128 : 384;
    int Xo = (i==0) ? 0 : (i-1)*128;
    gemm_tok<EPI_PLAIN,false><<<dim3(1,128,3), 256, 0, stream>>>(
        wq, wk, wv, OFF_QB, OFF_KB, OFF_VB,
        XiOff, Xs, Xo, 128, 0, nullptr, nullptr,
        nullptr, 0, 0, 0, 0, 0, 128, 128);
    attn_kernel<<<dim3(4096), 256, 0, stream>>>(OFF_QB, OFF_KB, OFF_VB, OFF_IDX, in, wp, OFF_AGG);
    gemm_tok<EPI_RES,false><<<dim3(1,128,1), 256, 0, stream>>>(
        wo, wo, wo, OFF_XCAT, OFF_XCAT, OFF_XCAT,
        OFF_AGG, 128, 0, 384, i*128, si, bi,
        nullptr, 0, 0, XiOff, Xs, Xo, 128, 128);
  }
  // 8: fuse (leaky relu)
  gemm_tok<EPI_LEAKY,false><<<dim3(8,128,1), 256, 0, stream>>>(
      OFF_WFUSE, OFF_WFUSE, OFF_WFUSE, OFF_XF, OFF_XF, OFF_XF,
      OFF_XCAT, 384, 0, 1024, 0, fuse_s, fuse_b,
      nullptr, 0, 0, 0, 0, 0, 384, 384);
  // 9-10: pooling + broadcast-g term of cls1 (fp32)
  pool_kernel<<<dim3(64), 256, 0, stream>>>(OFF_XF, OFF_G);
  gterm_kernel<<<dim3(8), 256, 0, stream>>>(cls_w1, cls_b1, OFF_G, OFF_GB);
  // 11: cls1 (K=1024 x-half of W1; gb = W1[:,1024:]@g + bias1 as extra)
  gemm_tok<EPI_CLS,false><<<dim3(4,128,1), 256, 0, stream>>>(
      OFF_WW1, OFF_WW1, OFF_WW1, OFF_C1, OFF_C1, OFF_C1,
      OFF_XF, 1024, 0, 512, 0, cls_s1, cls_sh1,
      nullptr, OFF_GB, 512, 0, 0, 0, 1024, 1024);
  // 12: cls2
  gemm_tok<EPI_CLS,true><<<dim3(2,128,1), 256, 0, stream>>>(
      OFF_WW2, OFF_WW2, OFF_WW2, OFF_C2, OFF_C2, OFF_C2,
      OFF_C1, 512, 0, 256, 0, cls_s2, cls_sh2,
      cls_b2, 0, 0, 0, 0, 0, 512, 512);
  // 13: cls3 -> d_out (fp32)
  cls3_kernel<<<dim3(256), 256, 0, stream>>>(OFF_C2, cls_w3, cls_b3, outp);
}